// Round 10
// baseline (184.976 us; speedup 1.0000x reference)
//
#include <hip/hip_runtime.h>
#include <math.h>

typedef _Float16 f16;
typedef __attribute__((ext_vector_type(4))) _Float16 f16x4;
typedef __attribute__((ext_vector_type(8))) _Float16 f16x8;
typedef __attribute__((ext_vector_type(2))) __fp16 h16x2;
typedef __attribute__((ext_vector_type(4))) __fp16 h16x4;
typedef __attribute__((ext_vector_type(4))) float f32x4;

// async global->LDS, 16B per lane, dest = wave-uniform base + lane*16
__device__ __forceinline__ void load_lds16(const void* g, void* l) {
    __builtin_amdgcn_global_load_lds((const __attribute__((address_space(1))) void*)g,
                                     (__attribute__((address_space(3))) void*)l, 16, 0, 0);
}

// raw v_exp_f32 (no ocml range-fixup wrapper)
__device__ __forceinline__ float fast_exp2(float x) {
#if __has_builtin(__builtin_amdgcn_exp2f)
    return __builtin_amdgcn_exp2f(x);
#else
    return __exp2f(x);
#endif
}

#define MFMA32(a, b, c) __builtin_amdgcn_mfma_f32_16x16x32_f16(a, b, c, 0, 0, 0)
#define MFMA16(a, b, c) __builtin_amdgcn_mfma_f32_16x16x16f16(a, b, c, 0, 0, 0)

// ---------------------------------------------------------------------------
// Kernel 1: QKV GEMM with fused x-transpose.
// C[m][n] = sum_k wqkv[m][k](fp32) * x^T[n][k], x given as [c 256][p 4096] fp32.
// Per k-tile: stage x[64c][64p] fp32 into pad-68 LDS, transpose+cvt -> Bs
// (swizzled f16 [p][c]), A = wqkv fp32 -> f16. BM=128, BN=64, grid (64,12).
// Epilogue via Ts transpose:
//   q/k -> [head][p][d] coalesced 16B (q pre-scaled 0.125*log2e)
//   v   -> per-head [p4][d][4] quad-interleaved (attn B-frag lane-linear)
// ---------------------------------------------------------------------------
__global__ __launch_bounds__(256) void gemm_qkv(
        const float* __restrict__ A, const float* __restrict__ xg,
        f16* __restrict__ qb, f16* __restrict__ kb, f16* __restrict__ vb) {
    __shared__ __align__(16) char smem[41984];
    f16* As = (f16*)smem;                    // 128 x 64 f16 = 16 KB
    f16* Bs = (f16*)(smem + 16384);          // 64 x 64 f16  =  8 KB
    float* Xs = (float*)(smem + 24576);      // 64 x 68 fp32 = 17408 B
    const int K = 256, tid = threadIdx.x;
    const int w = tid >> 6, lane = tid & 63, l16 = lane & 15, g = lane >> 4;
    const int wm = w >> 1, wn = w & 1;
    const int mBase = blockIdx.y * 128, nBase = blockIdx.x * 64;
    const int swz = lane & 7;

    f32x4 acc[4][2] = {};
    const int srow = tid >> 1;
    const int sc0 = (tid & 1) * 4;
    const int xc = tid >> 2;                 // x-stage: c row 0..63
    const int xp = (tid & 3) * 16;           // x-stage: p chunk base
    const int tp = tid & 63;                 // transpose: p row
    const int tc = (tid >> 6) * 2;           // transpose: first c8 chunk

    for (int k0 = 0; k0 < K; k0 += 64) {
        // stage1: x[k0+c][nBase+p] fp32 -> Xs[c][p] (pad 68)
        for (int q = 0; q < 4; q++) {
            float4 v = *(const float4*)&xg[(size_t)(k0 + xc) * 4096 + nBase + xp + q * 4];
            *(float4*)&Xs[xc * 68 + xp + q * 4] = v;
        }
        // A staging (fp32 -> f16, swizzled)
        for (int cc = 0; cc < 4; cc++) {
            const int c = sc0 + cc;
            const float* ap = A + (size_t)(mBase + srow) * K + k0 + c * 8;
            float4 u0 = *(const float4*)ap;
            float4 u1 = *(const float4*)(ap + 4);
            f16x8 hv;
            hv[0] = (f16)u0.x; hv[1] = (f16)u0.y; hv[2] = (f16)u0.z; hv[3] = (f16)u0.w;
            hv[4] = (f16)u1.x; hv[5] = (f16)u1.y; hv[6] = (f16)u1.z; hv[7] = (f16)u1.w;
            *(f16x8*)&As[srow * 64 + ((c ^ (srow & 7)) * 8)] = hv;
        }
        __syncthreads();
        // stage2: transpose Xs -> Bs[p][c] f16, chunk-swizzled by p&7
        for (int cc = 0; cc < 2; cc++) {
            const int c8 = tc + cc;
            f16x8 hv;
            for (int e = 0; e < 8; e++)
                hv[e] = (f16)Xs[(c8 * 8 + e) * 68 + tp];
            *(f16x8*)&Bs[tp * 64 + ((c8 ^ (tp & 7)) * 8)] = hv;
        }
        __syncthreads();
        for (int ks = 0; ks < 2; ks++) {
            const int ch = ((ks * 4 + g) ^ swz) * 8;
            f16x8 af[4], bf[2];
            for (int t = 0; t < 4; t++)
                af[t] = *(const f16x8*)&As[(wm * 64 + t * 16 + l16) * 64 + ch];
            for (int t = 0; t < 2; t++)
                bf[t] = *(const f16x8*)&Bs[(wn * 32 + t * 16 + l16) * 64 + ch];
            for (int mt = 0; mt < 4; mt++)
                for (int nt = 0; nt < 2; nt++)
                    acc[mt][nt] = MFMA32(af[mt], bf[nt], acc[mt][nt]);
        }
        __syncthreads();
    }

    // -------- epilogue: Ts[p_local 64][o_local 128], stride 136 --------
    const int which = mBase >> 9;  // 0=q, 1=k, 2=v (block-uniform)
    const float sc = (which == 0) ? 0.18033688011112042f : 1.0f;  // 0.125*log2e
    f16* Ts = (f16*)smem;  // 64 x 136 x 2B = 17408 B
    for (int mt = 0; mt < 4; mt++)
        for (int nt = 0; nt < 2; nt++)
            for (int r = 0; r < 4; r++)
                Ts[(wn * 32 + nt * 16 + l16) * 136 + wm * 64 + mt * 16 + g * 4 + r] =
                    (f16)(acc[mt][nt][r] * sc);
    __syncthreads();
    if (which < 2) {
        f16* tgt = (which == 0) ? qb : kb;
        const int row = tid >> 2;                 // p_local
        const int p = nBase + row;
        for (int cc = 0; cc < 4; cc++) {
            const int c8 = (tid & 3) * 4 + cc;    // 8-f16 chunk of o (0..15)
            f16x8 v = *(const f16x8*)&Ts[row * 136 + c8 * 8];
            const int o = mBase + c8 * 8;
            const int head = (o >> 6) & 7;
            const int d = o & 63;
            *(f16x8*)&tgt[(size_t)head * 262144 + (size_t)p * 64 + d] = v;
        }
    } else {
        // V: chunk = (p4, d-pair): 16B = [d0: p0..p3][d0+1: p0..p3]
        const int h0 = (mBase - 1024) >> 6;
        const int dp = tid & 63;                  // d-pair index over 128 o
        const int head = h0 + (dp >> 5);
        const int d0 = (dp * 2) & 63;
        const int o0 = dp * 2;
        for (int cc = 0; cc < 4; cc++) {
            const int p4l = (tid >> 6) * 4 + cc;  // 0..15
            f16x8 vv;
            for (int pp = 0; pp < 4; pp++) {
                vv[pp]     = Ts[(p4l * 4 + pp) * 136 + o0];
                vv[4 + pp] = Ts[(p4l * 4 + pp) * 136 + o0 + 1];
            }
            const size_t p4g = (size_t)(nBase >> 2) + p4l;
            *(f16x8*)&vb[(size_t)head * 262144 + p4g * 256 + d0 * 4] = vv;
        }
    }
}

// ---------------------------------------------------------------------------
// Kernel 2: flash attention — NO LDS, NO BARRIERS. Every wave independent.
// K/V fragments load straight global->VGPR (L2-resident; h=bx&7 XCD affinity).
// S^T = K*Q^T (mfma 16x16x32): C-layout IS the A-layout of mfma 16x16x16,
// so P = exp2(S^T) feeds PV from registers. Raw v_exp_f32.
// Each wave owns 64 i-rows (Q + O accum in regs) x a 1024-j quarter stream.
// grid = 512: h (8) x it (16, 256 i per block) x s (4 j-splits). 2 blocks/CU.
// ---------------------------------------------------------------------------
__global__ __launch_bounds__(256, 2) void attn_fwd(
        const f16* __restrict__ qb, const f16* __restrict__ kb,
        const f16* __restrict__ vb, f16* __restrict__ Op, float* __restrict__ Lp) {
    const int tid = threadIdx.x;
    const int w = tid >> 6, lane = tid & 63, l16 = lane & 15, g = lane >> 4;
    const int bx = blockIdx.x;
    const int h = bx & 7, rest = bx >> 3, it = rest >> 2, s = rest & 3;
    const f16* Qw = qb + (size_t)h * 262144 + (size_t)(it * 256 + w * 64) * 64;
    const f16* Kh = kb + (size_t)h * 262144 + (size_t)s * 65536;   // [j][d]
    const f16* Vh = vb + (size_t)h * 262144 + (size_t)s * 65536;   // [p4][d][4]

    // Q B-frags (16x16x32 B-layout: n=i=l16, k=d=ks*32+g*8..+7)
    f16x8 aq[4][2];
#pragma unroll
    for (int ib = 0; ib < 4; ib++)
#pragma unroll
        for (int ks = 0; ks < 2; ks++)
            aq[ib][ks] = *(const f16x8*)(Qw + (ib * 16 + l16) * 64 + ks * 32 + g * 8);

    f32x4 oacc[4][4] = {};
    float lsum[4] = {0.f, 0.f, 0.f, 0.f};
    const h16x2 one2 = {(__fp16)1.0f, (__fp16)1.0f};
    // lane-linear global bases for K-frag (A) and V-frag (B) reads
    const f16* Kl = Kh + l16 * 64 + g * 8;     // + row*64; kf1 at +32
    const f16* Vl = Vh + g * 256 + l16 * 4;    // + jt*4096 + nt*1024 + dn*64

#pragma unroll 2
    for (int jt = 0; jt < 16; jt++) {
#pragma unroll
        for (int nt = 0; nt < 4; nt++) {
            const f16* kp = Kl + (jt * 64 + nt * 16) * 64;
            f16x8 kf0 = *(const f16x8*)(kp);
            f16x8 kf1 = *(const f16x8*)(kp + 32);
            f32x4 sT[4];
#pragma unroll
            for (int ib = 0; ib < 4; ib++) {
                f32x4 z = {};
                z = MFMA32(kf0, aq[ib][0], z);
                sT[ib] = MFMA32(kf1, aq[ib][1], z);
            }
            f16x4 ap[4];
#pragma unroll
            for (int ib = 0; ib < 4; ib++) {
                h16x2 a01 = __builtin_amdgcn_cvt_pkrtz(fast_exp2(sT[ib][0]), fast_exp2(sT[ib][1]));
                h16x2 a23 = __builtin_amdgcn_cvt_pkrtz(fast_exp2(sT[ib][2]), fast_exp2(sT[ib][3]));
                lsum[ib] = __builtin_amdgcn_fdot2(a01, one2, lsum[ib], false);
                lsum[ib] = __builtin_amdgcn_fdot2(a23, one2, lsum[ib], false);
                ap[ib] = __builtin_bit_cast(f16x4, __builtin_shufflevector(a01, a23, 0, 1, 2, 3));
            }
            const f16* vp = Vl + jt * 4096 + nt * 1024;
#pragma unroll
            for (int dn = 0; dn < 4; dn++) {
                f16x4 bv = *(const f16x4*)(vp + dn * 64);
                oacc[0][dn] = MFMA16(ap[0], bv, oacc[0][dn]);
                oacc[1][dn] = MFMA16(ap[1], bv, oacc[1][dn]);
                oacc[2][dn] = MFMA16(ap[2], bv, oacc[2][dn]);
                oacc[3][dn] = MFMA16(ap[3], bv, oacc[3][dn]);
            }
        }
    }
    // row-sum: lane holds partial for i=l16; reduce across the 4 g-groups
#pragma unroll
    for (int ib = 0; ib < 4; ib++) {
        lsum[ib] += __shfl_xor(lsum[ib], 16);
        lsum[ib] += __shfl_xor(lsum[ib], 32);
    }
    if (lane < 16)
#pragma unroll
        for (int ib = 0; ib < 4; ib++)
            Lp[(size_t)s * 32768 + (size_t)(it * 256 + w * 64 + ib * 16 + l16) * 8 + h] =
                lsum[ib];
    // O store (C-layout: col=d=l16, row=i_local=g*4+r), unnormalized f16
    f16* Oh = Op + (size_t)s * 2097152 + (size_t)(it * 256 + w * 64) * 512 + h * 64;
#pragma unroll
    for (int ib = 0; ib < 4; ib++)
        for (int dn = 0; dn < 4; dn++)
            for (int r = 0; r < 4; r++) {
                const int i = ib * 16 + g * 4 + r;
                Oh[(size_t)i * 512 + dn * 16 + l16] = (f16)oacc[ib][dn][r];
            }
}

// ---------------------------------------------------------------------------
// Kernel 3: out GEMM with fused combine. C[o][p] = wout . (sum_s Op_s)/l + b.
// BM=64, BN=32 -> grid (128,4)=512 blocks (2/CU). B-staging sums 4 quarters
// (packed f16) and normalizes by invL (per-(p,h), computed once into LDS).
// ---------------------------------------------------------------------------
__global__ __launch_bounds__(256) void gemm_out(
        const float* __restrict__ A, const f16* __restrict__ Op,
        const float* __restrict__ Lp, const float* __restrict__ bias,
        float* __restrict__ C) {
    __shared__ __align__(16) char smem[13312];
    f16* As = (f16*)smem;                  // 64 x 64 = 8 KB
    f16* Bs = (f16*)(smem + 8192);         // 32 x 64 = 4 KB
    float* invL = (float*)(smem + 12288);  // 32 p x 8 h
    const int tid = threadIdx.x;
    const int w = tid >> 6, lane = tid & 63, l16 = lane & 15, g = lane >> 4;
    const int wm = w >> 1, wn = w & 1;
    const int mBase = blockIdx.y * 64, nBase = blockIdx.x * 32;
    const int swz = lane & 7;

    {
        const int p = nBase + (tid >> 3), hh = tid & 7;
        float sum = 0.f;
        for (int s4 = 0; s4 < 4; s4++) sum += Lp[(size_t)s4 * 32768 + p * 8 + hh];
        invL[tid] = 1.0f / sum;
    }
    __syncthreads();

    f32x4 acc[2] = {};
    const int srow = tid >> 2;
    const int sc0 = (tid & 3) * 2;

    for (int k0 = 0; k0 < 512; k0 += 64) {
        for (int cc = 0; cc < 2; cc++) {
            const int c = sc0 + cc;
            const float* ap = A + (size_t)(mBase + srow) * 512 + k0 + c * 8;
            float4 u0 = *(const float4*)ap;
            float4 u1 = *(const float4*)(ap + 4);
            f16x8 hv;
            hv[0] = (f16)u0.x; hv[1] = (f16)u0.y; hv[2] = (f16)u0.z; hv[3] = (f16)u0.w;
            hv[4] = (f16)u1.x; hv[5] = (f16)u1.y; hv[6] = (f16)u1.z; hv[7] = (f16)u1.w;
            *(f16x8*)&As[srow * 64 + ((c ^ (srow & 7)) * 8)] = hv;
        }
        // B stage: combine 4 Op quarters + normalize, swizzled ds_write
        const int hk = k0 >> 6;               // head for this k-tile (uniform)
        {
            const int row = tid >> 3, ch = tid & 7;
            const int gc = ch ^ (row & 7);
            const f16* op0 = Op + (size_t)(nBase + row) * 512 + k0 + gc * 8;
            f16x8 b0 = *(const f16x8*)(op0);
            f16x8 b1 = *(const f16x8*)(op0 + 2097152);
            f16x8 b2 = *(const f16x8*)(op0 + 4194304);
            f16x8 b3 = *(const f16x8*)(op0 + 6291456);
            const f16 iv = (f16)invL[row * 8 + hk];
            f16x8 bsum = (b0 + b1) + (b2 + b3);
            bsum = bsum * iv;
            *(f16x8*)&Bs[tid * 8] = bsum;
        }
        __syncthreads();
        for (int ks = 0; ks < 2; ks++) {
            const int chv = ((ks * 4 + g) ^ swz) * 8;
            f16x8 af[2], bf;
            for (int t = 0; t < 2; t++)
                af[t] = *(const f16x8*)&As[(wm * 32 + t * 16 + l16) * 64 + chv];
            bf = *(const f16x8*)&Bs[(wn * 16 + l16) * 64 + chv];
            for (int mt = 0; mt < 2; mt++)
                acc[mt] = MFMA32(af[mt], bf, acc[mt]);
        }
        __syncthreads();
    }

    for (int mt = 0; mt < 2; mt++)
        for (int r = 0; r < 4; r++) {
            const int o = mBase + wm * 32 + mt * 16 + g * 4 + r;
            const float bb = bias[o];
            const int p = nBase + wn * 16 + l16;
            C[(size_t)o * 4096 + p] = acc[mt][r] + bb;
        }
}

// ---------------------------------------------------------------------------
extern "C" void kernel_launch(void* const* d_in, const int* in_sizes, int n_in,
                              void* d_out, int out_size, void* d_ws, size_t ws_size,
                              hipStream_t stream) {
    const float* x    = (const float*)d_in[0];  // (1,256,64,64)
    const float* wqkv = (const float*)d_in[1];  // (1536,256)
    const float* wout = (const float*)d_in[2];  // (256,512)
    const float* bout = (const float*)d_in[3];  // (256,)
    float* out = (float*)d_out;                 // (1,256,64,64)

    char* ws = (char*)d_ws;
    // lifetime-packed workspace (30 MB):
    float* Lp = (float*)(ws);                    // [0,512K) written by attn
    f16* qb = (f16*)(ws + (2u << 20));           // [2M,6M)
    f16* kb = (f16*)(ws + (6u << 20));           // [6M,10M)
    f16* vb = (f16*)(ws + (10u << 20));          // [10M,14M) [head][p4][d][4]
    f16* Op = (f16*)(ws + (14u << 20));          // [14M,30M) 4 split quarters

    gemm_qkv<<<dim3(64, 12), 256, 0, stream>>>(wqkv, x, qb, kb, vb);
    attn_fwd<<<dim3(512), 256, 0, stream>>>(qb, kb, vb, Op, Lp);
    gemm_out<<<dim3(128, 4), 256, 0, stream>>>(wout, Op, Lp, bout, out);
}

// Round 11
// 140.415 us; speedup vs baseline: 1.3174x; 1.3174x over previous
//
#include <hip/hip_runtime.h>
#include <math.h>

typedef _Float16 f16;
typedef __attribute__((ext_vector_type(4))) _Float16 f16x4;
typedef __attribute__((ext_vector_type(8))) _Float16 f16x8;
typedef __attribute__((ext_vector_type(2))) __fp16 h16x2;
typedef __attribute__((ext_vector_type(4))) __fp16 h16x4;
typedef __attribute__((ext_vector_type(4))) float f32x4;

// async global->LDS, 16B per lane, dest = wave-uniform base + lane*16
__device__ __forceinline__ void load_lds16(const void* g, void* l) {
    __builtin_amdgcn_global_load_lds((const __attribute__((address_space(1))) void*)g,
                                     (__attribute__((address_space(3))) void*)l, 16, 0, 0);
}

// raw v_exp_f32 (no ocml range-fixup wrapper)
__device__ __forceinline__ float fast_exp2(float x) {
#if __has_builtin(__builtin_amdgcn_exp2f)
    return __builtin_amdgcn_exp2f(x);
#else
    return __exp2f(x);
#endif
}

#define MFMA32(a, b, c) __builtin_amdgcn_mfma_f32_16x16x32_f16(a, b, c, 0, 0, 0)
#define MFMA16(a, b, c) __builtin_amdgcn_mfma_f32_16x16x16f16(a, b, c, 0, 0, 0)

// ---------------------------------------------------------------------------
// Kernel 1: QKV GEMM with fused x-transpose.
// C[m][n] = sum_k wqkv[m][k](fp32) * x^T[n][k], x given as [c 256][p 4096] fp32.
// Per k-tile: stage x[64c][64p] fp32 into pad-68 LDS, transpose+cvt -> Bs
// (swizzled f16 [p][c]), A = wqkv fp32 -> f16. BM=128, BN=64, grid (64,12).
// Epilogue via Ts transpose:
//   q/k -> [head][p][d] coalesced 16B (q pre-scaled 0.125*log2e)
//   v   -> per-head [p4][d][4] quad-interleaved (attn B-frag lane-linear)
// ---------------------------------------------------------------------------
__global__ __launch_bounds__(256) void gemm_qkv(
        const float* __restrict__ A, const float* __restrict__ xg,
        f16* __restrict__ qb, f16* __restrict__ kb, f16* __restrict__ vb) {
    __shared__ __align__(16) char smem[41984];
    f16* As = (f16*)smem;                    // 128 x 64 f16 = 16 KB
    f16* Bs = (f16*)(smem + 16384);          // 64 x 64 f16  =  8 KB
    float* Xs = (float*)(smem + 24576);      // 64 x 68 fp32 = 17408 B
    const int K = 256, tid = threadIdx.x;
    const int w = tid >> 6, lane = tid & 63, l16 = lane & 15, g = lane >> 4;
    const int wm = w >> 1, wn = w & 1;
    const int mBase = blockIdx.y * 128, nBase = blockIdx.x * 64;
    const int swz = lane & 7;

    f32x4 acc[4][2] = {};
    const int srow = tid >> 1;
    const int sc0 = (tid & 1) * 4;
    const int xc = tid >> 2;                 // x-stage: c row 0..63
    const int xp = (tid & 3) * 16;           // x-stage: p chunk base
    const int tp = tid & 63;                 // transpose: p row
    const int tc = (tid >> 6) * 2;           // transpose: first c8 chunk

    for (int k0 = 0; k0 < K; k0 += 64) {
        // stage1: x[k0+c][nBase+p] fp32 -> Xs[c][p] (pad 68)
        for (int q = 0; q < 4; q++) {
            float4 v = *(const float4*)&xg[(size_t)(k0 + xc) * 4096 + nBase + xp + q * 4];
            *(float4*)&Xs[xc * 68 + xp + q * 4] = v;
        }
        // A staging (fp32 -> f16, swizzled)
        for (int cc = 0; cc < 4; cc++) {
            const int c = sc0 + cc;
            const float* ap = A + (size_t)(mBase + srow) * K + k0 + c * 8;
            float4 u0 = *(const float4*)ap;
            float4 u1 = *(const float4*)(ap + 4);
            f16x8 hv;
            hv[0] = (f16)u0.x; hv[1] = (f16)u0.y; hv[2] = (f16)u0.z; hv[3] = (f16)u0.w;
            hv[4] = (f16)u1.x; hv[5] = (f16)u1.y; hv[6] = (f16)u1.z; hv[7] = (f16)u1.w;
            *(f16x8*)&As[srow * 64 + ((c ^ (srow & 7)) * 8)] = hv;
        }
        __syncthreads();
        // stage2: transpose Xs -> Bs[p][c] f16, chunk-swizzled by p&7
        for (int cc = 0; cc < 2; cc++) {
            const int c8 = tc + cc;
            f16x8 hv;
            for (int e = 0; e < 8; e++)
                hv[e] = (f16)Xs[(c8 * 8 + e) * 68 + tp];
            *(f16x8*)&Bs[tp * 64 + ((c8 ^ (tp & 7)) * 8)] = hv;
        }
        __syncthreads();
        for (int ks = 0; ks < 2; ks++) {
            const int ch = ((ks * 4 + g) ^ swz) * 8;
            f16x8 af[4], bf[2];
            for (int t = 0; t < 4; t++)
                af[t] = *(const f16x8*)&As[(wm * 64 + t * 16 + l16) * 64 + ch];
            for (int t = 0; t < 2; t++)
                bf[t] = *(const f16x8*)&Bs[(wn * 32 + t * 16 + l16) * 64 + ch];
            for (int mt = 0; mt < 4; mt++)
                for (int nt = 0; nt < 2; nt++)
                    acc[mt][nt] = MFMA32(af[mt], bf[nt], acc[mt][nt]);
        }
        __syncthreads();
    }

    // -------- epilogue: Ts[p_local 64][o_local 128], stride 136 --------
    const int which = mBase >> 9;  // 0=q, 1=k, 2=v (block-uniform)
    const float sc = (which == 0) ? 0.18033688011112042f : 1.0f;  // 0.125*log2e
    f16* Ts = (f16*)smem;  // 64 x 136 x 2B = 17408 B
    for (int mt = 0; mt < 4; mt++)
        for (int nt = 0; nt < 2; nt++)
            for (int r = 0; r < 4; r++)
                Ts[(wn * 32 + nt * 16 + l16) * 136 + wm * 64 + mt * 16 + g * 4 + r] =
                    (f16)(acc[mt][nt][r] * sc);
    __syncthreads();
    if (which < 2) {
        f16* tgt = (which == 0) ? qb : kb;
        const int row = tid >> 2;                 // p_local
        const int p = nBase + row;
        for (int cc = 0; cc < 4; cc++) {
            const int c8 = (tid & 3) * 4 + cc;    // 8-f16 chunk of o (0..15)
            f16x8 v = *(const f16x8*)&Ts[row * 136 + c8 * 8];
            const int o = mBase + c8 * 8;
            const int head = (o >> 6) & 7;
            const int d = o & 63;
            *(f16x8*)&tgt[(size_t)head * 262144 + (size_t)p * 64 + d] = v;
        }
    } else {
        // V: chunk = (p4, d-pair): 16B = [d0: p0..p3][d0+1: p0..p3]
        const int h0 = (mBase - 1024) >> 6;
        const int dp = tid & 63;                  // d-pair index over 128 o
        const int head = h0 + (dp >> 5);
        const int d0 = (dp * 2) & 63;
        const int o0 = dp * 2;
        for (int cc = 0; cc < 4; cc++) {
            const int p4l = (tid >> 6) * 4 + cc;  // 0..15
            f16x8 vv;
            for (int pp = 0; pp < 4; pp++) {
                vv[pp]     = Ts[(p4l * 4 + pp) * 136 + o0];
                vv[4 + pp] = Ts[(p4l * 4 + pp) * 136 + o0 + 1];
            }
            const size_t p4g = (size_t)(nBase >> 2) + p4l;
            *(f16x8*)&vb[(size_t)head * 262144 + p4g * 256 + d0 * 4] = vv;
        }
    }
}

// ---------------------------------------------------------------------------
// Kernel 2: flash attention — LDS-staged (R8 structure), 64 i-rows per wave.
// S^T = K*Q^T (mfma 16x16x32): C-layout IS the A-layout of mfma 16x16x16,
// so P = exp2(S^T) feeds PV from registers. Raw v_exp_f32; fdot2 row sums.
// K/V double-buffered via global_load_lds (prefetch 1 tile ahead); K-frag /
// V-frag ds_reads amortized over 4 i-blocks per wave (half LDS traffic/flop,
// half barriers/flop vs 32-i version). V per-head [p4][d][4] conflict-free.
// grid = 512: h=bx&7 (XCD L2 affinity), it (16, 256 i/block) x s (4 j-splits).
// ---------------------------------------------------------------------------
__global__ __launch_bounds__(256, 2) void attn_fwd(
        const f16* __restrict__ qb, const f16* __restrict__ kb,
        const f16* __restrict__ vb, f16* __restrict__ Op, float* __restrict__ Lp) {
    __shared__ __align__(16) char smem[32768];
    f16* Ks = (f16*)smem;                  // 2 x 8KB double buffer
    f16* Vs = (f16*)(smem + 16384);        // 2 x 8KB double buffer
    const int tid = threadIdx.x;
    const int w = tid >> 6, lane = tid & 63, l16 = lane & 15, g = lane >> 4;
    const int bx = blockIdx.x;
    const int h = bx & 7, rest = bx >> 3, it = rest >> 2, s = rest & 3;
    const f16* Qw = qb + (size_t)h * 262144 + (size_t)(it * 256 + w * 64) * 64;
    const f16* Kh = kb + (size_t)h * 262144 + (size_t)s * 65536;   // [j][d]
    const f16* Vh = vb + (size_t)h * 262144 + (size_t)s * 65536;   // [p4][d][4]

    // Q B-frags (16x16x32 B-layout: n=i=l16, k=d=ks*32+g*8..+7)
    f16x8 aq[4][2];
#pragma unroll
    for (int ib = 0; ib < 4; ib++)
#pragma unroll
        for (int ks = 0; ks < 2; ks++)
            aq[ib][ks] = *(const f16x8*)(Qw + (ib * 16 + l16) * 64 + ks * 32 + g * 8);

    // loop-invariant staging offsets (per-lane, hoisted)
    const int L0 = w * 64 + lane, L1 = 256 + w * 64 + lane;
    const int r0 = L0 >> 3, r1 = L1 >> 3;
    const int kO0 = r0 * 64 + (((L0 & 7) ^ (r0 & 7)) * 8);
    const int kO1 = r1 * 64 + (((L1 & 7) ^ (r1 & 7)) * 8);

    // stage K0 (row-swizzled) / V0 (contiguous 8KB)
    load_lds16(Kh + kO0, &Ks[L0 * 8]);
    load_lds16(Kh + kO1, &Ks[L1 * 8]);
    load_lds16(Vh + L0 * 8, &Vs[L0 * 8]);
    load_lds16(Vh + L1 * 8, &Vs[L1 * 8]);
    __syncthreads();

    f32x4 oacc[4][4] = {};
    float lsum[4] = {0.f, 0.f, 0.f, 0.f};
    const h16x2 one2 = {(__fp16)1.0f, (__fp16)1.0f};
    // loop-invariant lane bases for K-frag / V-frag LDS reads
    const f16* Kp0 = Ks + l16 * 64 + ((g ^ (l16 & 7)) * 8);
    const f16* Kp1 = Ks + l16 * 64 + (((g ^ 4) ^ (l16 & 7)) * 8);
    const f16* Vb = Vs + g * 256 + l16 * 4;

#pragma unroll
    for (int jt = 0; jt < 16; jt++) {
        const int cur = jt & 1;
        if (jt < 15) {
            const int nxt = cur ^ 1;
            const f16* Kt = Kh + (jt + 1) * 4096;
            const f16* Vt = Vh + (jt + 1) * 4096;
            load_lds16(Kt + kO0, &Ks[nxt * 4096 + L0 * 8]);
            load_lds16(Kt + kO1, &Ks[nxt * 4096 + L1 * 8]);
            load_lds16(Vt + L0 * 8, &Vs[nxt * 4096 + L0 * 8]);
            load_lds16(Vt + L1 * 8, &Vs[nxt * 4096 + L1 * 8]);
        }
        // nt-granular: QK(nt) -> exp(nt) -> PV(nt); short bursts mix pipes
#pragma unroll
        for (int nt = 0; nt < 4; nt++) {
            f16x8 kf0 = *(const f16x8*)(Kp0 + cur * 4096 + nt * 1024);
            f16x8 kf1 = *(const f16x8*)(Kp1 + cur * 4096 + nt * 1024);
            f32x4 sT[4];
#pragma unroll
            for (int ib = 0; ib < 4; ib++) {
                f32x4 z = {};
                z = MFMA32(kf0, aq[ib][0], z);
                sT[ib] = MFMA32(kf1, aq[ib][1], z);
            }
            f16x4 ap[4];
#pragma unroll
            for (int ib = 0; ib < 4; ib++) {
                h16x2 a01 = __builtin_amdgcn_cvt_pkrtz(fast_exp2(sT[ib][0]), fast_exp2(sT[ib][1]));
                h16x2 a23 = __builtin_amdgcn_cvt_pkrtz(fast_exp2(sT[ib][2]), fast_exp2(sT[ib][3]));
                lsum[ib] = __builtin_amdgcn_fdot2(a01, one2, lsum[ib], false);
                lsum[ib] = __builtin_amdgcn_fdot2(a23, one2, lsum[ib], false);
                ap[ib] = __builtin_bit_cast(f16x4, __builtin_shufflevector(a01, a23, 0, 1, 2, 3));
            }
#pragma unroll
            for (int dn = 0; dn < 4; dn++) {
                f16x4 bv = *(const f16x4*)(Vb + cur * 4096 + nt * 1024 + dn * 64);
                oacc[0][dn] = MFMA16(ap[0], bv, oacc[0][dn]);
                oacc[1][dn] = MFMA16(ap[1], bv, oacc[1][dn]);
                oacc[2][dn] = MFMA16(ap[2], bv, oacc[2][dn]);
                oacc[3][dn] = MFMA16(ap[3], bv, oacc[3][dn]);
            }
        }
        __syncthreads();
    }
    // row-sum: lane holds partial for i=l16; reduce across the 4 g-groups
#pragma unroll
    for (int ib = 0; ib < 4; ib++) {
        lsum[ib] += __shfl_xor(lsum[ib], 16);
        lsum[ib] += __shfl_xor(lsum[ib], 32);
    }
    if (lane < 16)
#pragma unroll
        for (int ib = 0; ib < 4; ib++)
            Lp[(size_t)s * 32768 + (size_t)(it * 256 + w * 64 + ib * 16 + l16) * 8 + h] =
                lsum[ib];
    // O store (C-layout: col=d=l16, row=i_local=g*4+r), unnormalized f16
    f16* Oh = Op + (size_t)s * 2097152 + (size_t)(it * 256 + w * 64) * 512 + h * 64;
#pragma unroll
    for (int ib = 0; ib < 4; ib++)
        for (int dn = 0; dn < 4; dn++)
            for (int r = 0; r < 4; r++) {
                const int i = ib * 16 + g * 4 + r;
                Oh[(size_t)i * 512 + dn * 16 + l16] = (f16)oacc[ib][dn][r];
            }
}

// ---------------------------------------------------------------------------
// Kernel 3: out GEMM with fused combine. C[o][p] = wout . (sum_s Op_s)/l + b.
// BM=64, BN=32 -> grid (128,4)=512 blocks (2/CU). B-staging sums 4 quarters
// (packed f16) and normalizes by invL (per-(p,h), computed once into LDS).
// ---------------------------------------------------------------------------
__global__ __launch_bounds__(256) void gemm_out(
        const float* __restrict__ A, const f16* __restrict__ Op,
        const float* __restrict__ Lp, const float* __restrict__ bias,
        float* __restrict__ C) {
    __shared__ __align__(16) char smem[13312];
    f16* As = (f16*)smem;                  // 64 x 64 = 8 KB
    f16* Bs = (f16*)(smem + 8192);         // 32 x 64 = 4 KB
    float* invL = (float*)(smem + 12288);  // 32 p x 8 h
    const int tid = threadIdx.x;
    const int w = tid >> 6, lane = tid & 63, l16 = lane & 15, g = lane >> 4;
    const int wm = w >> 1, wn = w & 1;
    const int mBase = blockIdx.y * 64, nBase = blockIdx.x * 32;
    const int swz = lane & 7;

    {
        const int p = nBase + (tid >> 3), hh = tid & 7;
        float sum = 0.f;
        for (int s4 = 0; s4 < 4; s4++) sum += Lp[(size_t)s4 * 32768 + p * 8 + hh];
        invL[tid] = 1.0f / sum;
    }
    __syncthreads();

    f32x4 acc[2] = {};
    const int srow = tid >> 2;
    const int sc0 = (tid & 3) * 2;

    for (int k0 = 0; k0 < 512; k0 += 64) {
        for (int cc = 0; cc < 2; cc++) {
            const int c = sc0 + cc;
            const float* ap = A + (size_t)(mBase + srow) * 512 + k0 + c * 8;
            float4 u0 = *(const float4*)ap;
            float4 u1 = *(const float4*)(ap + 4);
            f16x8 hv;
            hv[0] = (f16)u0.x; hv[1] = (f16)u0.y; hv[2] = (f16)u0.z; hv[3] = (f16)u0.w;
            hv[4] = (f16)u1.x; hv[5] = (f16)u1.y; hv[6] = (f16)u1.z; hv[7] = (f16)u1.w;
            *(f16x8*)&As[srow * 64 + ((c ^ (srow & 7)) * 8)] = hv;
        }
        // B stage: combine 4 Op quarters + normalize, swizzled ds_write
        const int hk = k0 >> 6;               // head for this k-tile (uniform)
        {
            const int row = tid >> 3, ch = tid & 7;
            const int gc = ch ^ (row & 7);
            const f16* op0 = Op + (size_t)(nBase + row) * 512 + k0 + gc * 8;
            f16x8 b0 = *(const f16x8*)(op0);
            f16x8 b1 = *(const f16x8*)(op0 + 2097152);
            f16x8 b2 = *(const f16x8*)(op0 + 4194304);
            f16x8 b3 = *(const f16x8*)(op0 + 6291456);
            const f16 iv = (f16)invL[row * 8 + hk];
            f16x8 bsum = (b0 + b1) + (b2 + b3);
            bsum = bsum * iv;
            *(f16x8*)&Bs[tid * 8] = bsum;
        }
        __syncthreads();
        for (int ks = 0; ks < 2; ks++) {
            const int chv = ((ks * 4 + g) ^ swz) * 8;
            f16x8 af[2], bf;
            for (int t = 0; t < 2; t++)
                af[t] = *(const f16x8*)&As[(wm * 32 + t * 16 + l16) * 64 + chv];
            bf = *(const f16x8*)&Bs[(wn * 16 + l16) * 64 + chv];
            for (int mt = 0; mt < 2; mt++)
                acc[mt] = MFMA32(af[mt], bf, acc[mt]);
        }
        __syncthreads();
    }

    for (int mt = 0; mt < 2; mt++)
        for (int r = 0; r < 4; r++) {
            const int o = mBase + wm * 32 + mt * 16 + g * 4 + r;
            const float bb = bias[o];
            const int p = nBase + wn * 16 + l16;
            C[(size_t)o * 4096 + p] = acc[mt][r] + bb;
        }
}

// ---------------------------------------------------------------------------
extern "C" void kernel_launch(void* const* d_in, const int* in_sizes, int n_in,
                              void* d_out, int out_size, void* d_ws, size_t ws_size,
                              hipStream_t stream) {
    const float* x    = (const float*)d_in[0];  // (1,256,64,64)
    const float* wqkv = (const float*)d_in[1];  // (1536,256)
    const float* wout = (const float*)d_in[2];  // (256,512)
    const float* bout = (const float*)d_in[3];  // (256,)
    float* out = (float*)d_out;                 // (1,256,64,64)

    char* ws = (char*)d_ws;
    // lifetime-packed workspace (30 MB):
    float* Lp = (float*)(ws);                    // [0,512K) written by attn
    f16* qb = (f16*)(ws + (2u << 20));           // [2M,6M)
    f16* kb = (f16*)(ws + (6u << 20));           // [6M,10M)
    f16* vb = (f16*)(ws + (10u << 20));          // [10M,14M) [head][p4][d][4]
    f16* Op = (f16*)(ws + (14u << 20));          // [14M,30M) 4 split quarters

    gemm_qkv<<<dim3(64, 12), 256, 0, stream>>>(wqkv, x, qb, kb, vb);
    attn_fwd<<<dim3(512), 256, 0, stream>>>(qb, kb, vb, Op, Lp);
    gemm_out<<<dim3(128, 4), 256, 0, stream>>>(wout, Op, Lp, bout, out);
}

// Round 12
// 138.127 us; speedup vs baseline: 1.3392x; 1.0166x over previous
//
#include <hip/hip_runtime.h>
#include <math.h>

typedef _Float16 f16;
typedef __attribute__((ext_vector_type(4))) _Float16 f16x4;
typedef __attribute__((ext_vector_type(8))) _Float16 f16x8;
typedef __attribute__((ext_vector_type(2))) __fp16 h16x2;
typedef __attribute__((ext_vector_type(4))) __fp16 h16x4;
typedef __attribute__((ext_vector_type(4))) float f32x4;

// async global->LDS, 16B per lane, dest = wave-uniform base + lane*16
__device__ __forceinline__ void load_lds16(const void* g, void* l) {
    __builtin_amdgcn_global_load_lds((const __attribute__((address_space(1))) void*)g,
                                     (__attribute__((address_space(3))) void*)l, 16, 0, 0);
}

// raw v_exp_f32 (no ocml range-fixup wrapper)
__device__ __forceinline__ float fast_exp2(float x) {
#if __has_builtin(__builtin_amdgcn_exp2f)
    return __builtin_amdgcn_exp2f(x);
#else
    return __exp2f(x);
#endif
}

#define MFMA32(a, b, c) __builtin_amdgcn_mfma_f32_16x16x32_f16(a, b, c, 0, 0, 0)

// ---------------------------------------------------------------------------
// Kernel 1: QKV GEMM with fused x-transpose.
// C[m][n] = sum_k wqkv[m][k](fp32) * x^T[n][k], x given as [c 256][p 4096] fp32.
// BM=128, BN=64, grid (64,12). Epilogues:
//   q/k -> [head][p][d] coalesced 16B via Ts transpose (q pre-scaled)
//   v   -> [head][d][p] direct from acc C-layout (row=o, col=p)
// ---------------------------------------------------------------------------
__global__ __launch_bounds__(256) void gemm_qkv(
        const float* __restrict__ A, const float* __restrict__ xg,
        f16* __restrict__ qb, f16* __restrict__ kb, f16* __restrict__ vb) {
    __shared__ __align__(16) char smem[41984];
    f16* As = (f16*)smem;                    // 128 x 64 f16 = 16 KB
    f16* Bs = (f16*)(smem + 16384);          // 64 x 64 f16  =  8 KB
    float* Xs = (float*)(smem + 24576);      // 64 x 68 fp32 = 17408 B
    const int K = 256, tid = threadIdx.x;
    const int w = tid >> 6, lane = tid & 63, l16 = lane & 15, g = lane >> 4;
    const int wm = w >> 1, wn = w & 1;
    const int mBase = blockIdx.y * 128, nBase = blockIdx.x * 64;
    const int swz = lane & 7;

    f32x4 acc[4][2] = {};
    const int srow = tid >> 1;
    const int sc0 = (tid & 1) * 4;
    const int xc = tid >> 2;                 // x-stage: c row 0..63
    const int xp = (tid & 3) * 16;           // x-stage: p chunk base
    const int tp = tid & 63;                 // transpose: p row
    const int tc = (tid >> 6) * 2;           // transpose: first c8 chunk

    for (int k0 = 0; k0 < K; k0 += 64) {
        // stage1: x[k0+c][nBase+p] fp32 -> Xs[c][p] (pad 68)
        for (int q = 0; q < 4; q++) {
            float4 v = *(const float4*)&xg[(size_t)(k0 + xc) * 4096 + nBase + xp + q * 4];
            *(float4*)&Xs[xc * 68 + xp + q * 4] = v;
        }
        // A staging (fp32 -> f16, swizzled)
        for (int cc = 0; cc < 4; cc++) {
            const int c = sc0 + cc;
            const float* ap = A + (size_t)(mBase + srow) * K + k0 + c * 8;
            float4 u0 = *(const float4*)ap;
            float4 u1 = *(const float4*)(ap + 4);
            f16x8 hv;
            hv[0] = (f16)u0.x; hv[1] = (f16)u0.y; hv[2] = (f16)u0.z; hv[3] = (f16)u0.w;
            hv[4] = (f16)u1.x; hv[5] = (f16)u1.y; hv[6] = (f16)u1.z; hv[7] = (f16)u1.w;
            *(f16x8*)&As[srow * 64 + ((c ^ (srow & 7)) * 8)] = hv;
        }
        __syncthreads();
        // stage2: transpose Xs -> Bs[p][c] f16, chunk-swizzled by p&7
        for (int cc = 0; cc < 2; cc++) {
            const int c8 = tc + cc;
            f16x8 hv;
            for (int e = 0; e < 8; e++)
                hv[e] = (f16)Xs[(c8 * 8 + e) * 68 + tp];
            *(f16x8*)&Bs[tp * 64 + ((c8 ^ (tp & 7)) * 8)] = hv;
        }
        __syncthreads();
        for (int ks = 0; ks < 2; ks++) {
            const int ch = ((ks * 4 + g) ^ swz) * 8;
            f16x8 af[4], bf[2];
            for (int t = 0; t < 4; t++)
                af[t] = *(const f16x8*)&As[(wm * 64 + t * 16 + l16) * 64 + ch];
            for (int t = 0; t < 2; t++)
                bf[t] = *(const f16x8*)&Bs[(wn * 32 + t * 16 + l16) * 64 + ch];
            for (int mt = 0; mt < 4; mt++)
                for (int nt = 0; nt < 2; nt++)
                    acc[mt][nt] = MFMA32(af[mt], bf[nt], acc[mt][nt]);
        }
        __syncthreads();
    }

    const int which = mBase >> 9;  // 0=q, 1=k, 2=v (block-uniform)
    if (which < 2) {
        // -------- epilogue via Ts[p_local 64][o_local 128], stride 136 ----
        const float sc = (which == 0) ? 0.18033688011112042f : 1.0f;  // 0.125*log2e
        f16* Ts = (f16*)smem;  // 64 x 136 x 2B = 17408 B
        __syncthreads();
        for (int mt = 0; mt < 4; mt++)
            for (int nt = 0; nt < 2; nt++)
                for (int r = 0; r < 4; r++)
                    Ts[(wn * 32 + nt * 16 + l16) * 136 + wm * 64 + mt * 16 + g * 4 + r] =
                        (f16)(acc[mt][nt][r] * sc);
        __syncthreads();
        f16* tgt = (which == 0) ? qb : kb;
        const int row = tid >> 2;                 // p_local
        const int p = nBase + row;
        for (int cc = 0; cc < 4; cc++) {
            const int c8 = (tid & 3) * 4 + cc;    // 8-f16 chunk of o (0..15)
            f16x8 v = *(const f16x8*)&Ts[row * 136 + c8 * 8];
            const int o = mBase + c8 * 8;
            const int head = (o >> 6) & 7;
            const int d = o & 63;
            *(f16x8*)&tgt[(size_t)head * 262144 + (size_t)p * 64 + d] = v;
        }
    } else {
        // V: direct from C-layout into [head][d][p]
        for (int mt = 0; mt < 4; mt++)
            for (int nt = 0; nt < 2; nt++)
                for (int r = 0; r < 4; r++) {
                    const int o = mBase + wm * 64 + mt * 16 + g * 4 + r;
                    const int p = nBase + wn * 32 + nt * 16 + l16;
                    const int vd = o - 1024;
                    vb[(size_t)(vd >> 6) * 262144 + (size_t)(vd & 63) * 4096 + p] =
                        (f16)acc[mt][nt][r];
                }
    }
}

// ---------------------------------------------------------------------------
// Kernel 2: flash attention — all-MFMA32 (K=32 PV via wave-private P buffer).
// S^T = K*Q^T (mfma 16x16x32). P = exp2(S^T) packed f16 and round-tripped
// through a per-wave LDS buffer (stride 72 B, conflict-free b64) to convert
// C-layout -> A-layout over K=32, so PV runs as MFMA32 (half the matrix-pipe
// issues of the MFMA16 version; MFMA16 measured ~same cost as MFMA32).
// V tiles [d 64][j 64] swizzled in LDS -> b128 B-frags, conflict-free.
// Raw v_exp_f32; fdot2 row sums. 64 i-rows per wave; grid 512 = 8h x 16it x 4s.
// ---------------------------------------------------------------------------
__global__ __launch_bounds__(256, 2) void attn_fwd(
        const f16* __restrict__ qb, const f16* __restrict__ kb,
        const f16* __restrict__ vb, f16* __restrict__ Op, float* __restrict__ Lp) {
    __shared__ __align__(16) char smem[51200];
    f16* Ks = (f16*)smem;                  // 2 x 8KB double buffer
    f16* Vs = (f16*)(smem + 16384);        // 2 x 8KB double buffer
    f16* Pb = (f16*)(smem + 32768);        // 4 waves x 64 rows x 72B
    const int tid = threadIdx.x;
    const int w = tid >> 6, lane = tid & 63, l16 = lane & 15, g = lane >> 4;
    const int bx = blockIdx.x;
    const int h = bx & 7, rest = bx >> 3, it = rest >> 2, s = rest & 3;
    const f16* Qw = qb + (size_t)h * 262144 + (size_t)(it * 256 + w * 64) * 64;
    const f16* Kh = kb + (size_t)h * 262144 + (size_t)s * 65536;   // [j][d]
    const f16* Vh = vb + (size_t)h * 262144 + (size_t)s * 1024;    // [d][j] + j-split

    // Q B-frags (16x16x32 B-layout: n=i=l16, k=d=ks*32+g*8..+7)
    f16x8 aq[4][2];
#pragma unroll
    for (int ib = 0; ib < 4; ib++)
#pragma unroll
        for (int ks = 0; ks < 2; ks++)
            aq[ib][ks] = *(const f16x8*)(Qw + (ib * 16 + l16) * 64 + ks * 32 + g * 8);

    // loop-invariant staging offsets (per-lane, hoisted)
    const int L0 = w * 64 + lane, L1 = 256 + w * 64 + lane;
    const int r0 = L0 >> 3, r1 = L1 >> 3;
    const int kO0 = r0 * 64 + (((L0 & 7) ^ (r0 & 7)) * 8);
    const int kO1 = r1 * 64 + (((L1 & 7) ^ (r1 & 7)) * 8);
    const int vO0 = r0 * 4096 + (((L0 & 7) ^ (r0 & 7)) * 8);   // V: row=d, 4096 stride
    const int vO1 = r1 * 4096 + (((L1 & 7) ^ (r1 & 7)) * 8);

    // stage K0/V0 (both row-chunk swizzled)
    load_lds16(Kh + kO0, &Ks[L0 * 8]);
    load_lds16(Kh + kO1, &Ks[L1 * 8]);
    load_lds16(Vh + vO0, &Vs[L0 * 8]);
    load_lds16(Vh + vO1, &Vs[L1 * 8]);
    __syncthreads();

    f32x4 oacc[4][4] = {};
    float lsum[4] = {0.f, 0.f, 0.f, 0.f};
    const h16x2 one2 = {(__fp16)1.0f, (__fp16)1.0f};
    // loop-invariant lane bases
    const f16* Kp0 = Ks + l16 * 64 + ((g ^ (l16 & 7)) * 8);
    const f16* Kp1 = Ks + l16 * 64 + (((g ^ 4) ^ (l16 & 7)) * 8);
    f16* Pw = Pb + w * 2304;                 // 64 rows x 36 f16 (72 B)
    f16* PwW = Pw + l16 * 36 + g * 4;        // write base (bytes: 72*l16+8g)
    const f16* PwR = Pw + l16 * 36 + g * 8;  // read base  (bytes: 72*l16+16g)

#pragma unroll
    for (int jt = 0; jt < 16; jt++) {
        const int cur = jt & 1;
        if (jt < 15) {
            const int nxt = cur ^ 1;
            const f16* Kt = Kh + (jt + 1) * 4096;
            const f16* Vt = Vh + (jt + 1) * 64;
            load_lds16(Kt + kO0, &Ks[nxt * 4096 + L0 * 8]);
            load_lds16(Kt + kO1, &Ks[nxt * 4096 + L1 * 8]);
            load_lds16(Vt + vO0, &Vs[nxt * 4096 + L0 * 8]);
            load_lds16(Vt + vO1, &Vs[nxt * 4096 + L1 * 8]);
        }
#pragma unroll
        for (int ntp = 0; ntp < 2; ntp++) {
            const int nt0 = ntp * 2, nt1 = ntp * 2 + 1;
            f16x8 kf00 = *(const f16x8*)(Kp0 + cur * 4096 + nt0 * 1024);
            f16x8 kf01 = *(const f16x8*)(Kp1 + cur * 4096 + nt0 * 1024);
            f16x8 kf10 = *(const f16x8*)(Kp0 + cur * 4096 + nt1 * 1024);
            f16x8 kf11 = *(const f16x8*)(Kp1 + cur * 4096 + nt1 * 1024);
            // QK + exp + pack + P->LDS (wave-private, no barrier)
#pragma unroll
            for (int ib = 0; ib < 4; ib++) {
                f32x4 sa = {}, sb = {};
                sa = MFMA32(kf00, aq[ib][0], sa);
                sa = MFMA32(kf01, aq[ib][1], sa);
                sb = MFMA32(kf10, aq[ib][0], sb);
                sb = MFMA32(kf11, aq[ib][1], sb);
                h16x2 a01 = __builtin_amdgcn_cvt_pkrtz(fast_exp2(sa[0]), fast_exp2(sa[1]));
                h16x2 a23 = __builtin_amdgcn_cvt_pkrtz(fast_exp2(sa[2]), fast_exp2(sa[3]));
                h16x2 b01 = __builtin_amdgcn_cvt_pkrtz(fast_exp2(sb[0]), fast_exp2(sb[1]));
                h16x2 b23 = __builtin_amdgcn_cvt_pkrtz(fast_exp2(sb[2]), fast_exp2(sb[3]));
                lsum[ib] = __builtin_amdgcn_fdot2(a01, one2, lsum[ib], false);
                lsum[ib] = __builtin_amdgcn_fdot2(a23, one2, lsum[ib], false);
                lsum[ib] = __builtin_amdgcn_fdot2(b01, one2, lsum[ib], false);
                lsum[ib] = __builtin_amdgcn_fdot2(b23, one2, lsum[ib], false);
                f16x4 apA = __builtin_bit_cast(f16x4, __builtin_shufflevector(a01, a23, 0, 1, 2, 3));
                f16x4 apB = __builtin_bit_cast(f16x4, __builtin_shufflevector(b01, b23, 0, 1, 2, 3));
                *(f16x4*)(PwW + ib * 576) = apA;         // j = g*4+r   (nt0)
                *(f16x4*)(PwW + ib * 576 + 16) = apB;    // j = 16+g*4+r (nt1)
            }
            // V B-frags (K=32: k=j=ntp*32+g*8..+7), b128 conflict-free
            f16x8 bv[4];
#pragma unroll
            for (int dn = 0; dn < 4; dn++)
                bv[dn] = *(const f16x8*)&Vs[cur * 4096 + (dn * 16 + l16) * 64 +
                                            (((ntp * 4 + g) ^ (l16 & 7)) * 8)];
            // PV as MFMA32: A = P rows (k=g*8..+7) from wave-private buffer
#pragma unroll
            for (int ib = 0; ib < 4; ib++) {
                f16x4 lo = *(const f16x4*)(PwR + ib * 576);
                f16x4 hi = *(const f16x4*)(PwR + ib * 576 + 4);
                f16x8 a8 = __builtin_shufflevector(lo, hi, 0, 1, 2, 3, 4, 5, 6, 7);
#pragma unroll
                for (int dn = 0; dn < 4; dn++)
                    oacc[ib][dn] = MFMA32(a8, bv[dn], oacc[ib][dn]);
            }
        }
        __syncthreads();
    }
    // row-sum: lane holds partial for i=l16; reduce across the 4 g-groups
#pragma unroll
    for (int ib = 0; ib < 4; ib++) {
        lsum[ib] += __shfl_xor(lsum[ib], 16);
        lsum[ib] += __shfl_xor(lsum[ib], 32);
    }
    if (lane < 16)
#pragma unroll
        for (int ib = 0; ib < 4; ib++)
            Lp[(size_t)s * 32768 + (size_t)(it * 256 + w * 64 + ib * 16 + l16) * 8 + h] =
                lsum[ib];
    // O store (C-layout: col=d=l16, row=i_local=g*4+r), unnormalized f16
    f16* Oh = Op + (size_t)s * 2097152 + (size_t)(it * 256 + w * 64) * 512 + h * 64;
#pragma unroll
    for (int ib = 0; ib < 4; ib++)
        for (int dn = 0; dn < 4; dn++)
            for (int r = 0; r < 4; r++) {
                const int i = ib * 16 + g * 4 + r;
                Oh[(size_t)i * 512 + dn * 16 + l16] = (f16)oacc[ib][dn][r];
            }
}

// ---------------------------------------------------------------------------
// Kernel 3: out GEMM with fused combine. C[o][p] = wout . (sum_s Op_s)/l + b.
// BM=64, BN=32 -> grid (128,4)=512 blocks. B-staging sums 4 quarters and
// normalizes by invL (per-(p,h), computed once into LDS).
// ---------------------------------------------------------------------------
__global__ __launch_bounds__(256) void gemm_out(
        const float* __restrict__ A, const f16* __restrict__ Op,
        const float* __restrict__ Lp, const float* __restrict__ bias,
        float* __restrict__ C) {
    __shared__ __align__(16) char smem[13312];
    f16* As = (f16*)smem;                  // 64 x 64 = 8 KB
    f16* Bs = (f16*)(smem + 8192);         // 32 x 64 = 4 KB
    float* invL = (float*)(smem + 12288);  // 32 p x 8 h
    const int tid = threadIdx.x;
    const int w = tid >> 6, lane = tid & 63, l16 = lane & 15, g = lane >> 4;
    const int wm = w >> 1, wn = w & 1;
    const int mBase = blockIdx.y * 64, nBase = blockIdx.x * 32;
    const int swz = lane & 7;

    {
        const int p = nBase + (tid >> 3), hh = tid & 7;
        float sum = 0.f;
        for (int s4 = 0; s4 < 4; s4++) sum += Lp[(size_t)s4 * 32768 + p * 8 + hh];
        invL[tid] = 1.0f / sum;
    }
    __syncthreads();

    f32x4 acc[2] = {};
    const int srow = tid >> 2;
    const int sc0 = (tid & 3) * 2;

    for (int k0 = 0; k0 < 512; k0 += 64) {
        for (int cc = 0; cc < 2; cc++) {
            const int c = sc0 + cc;
            const float* ap = A + (size_t)(mBase + srow) * 512 + k0 + c * 8;
            float4 u0 = *(const float4*)ap;
            float4 u1 = *(const float4*)(ap + 4);
            f16x8 hv;
            hv[0] = (f16)u0.x; hv[1] = (f16)u0.y; hv[2] = (f16)u0.z; hv[3] = (f16)u0.w;
            hv[4] = (f16)u1.x; hv[5] = (f16)u1.y; hv[6] = (f16)u1.z; hv[7] = (f16)u1.w;
            *(f16x8*)&As[srow * 64 + ((c ^ (srow & 7)) * 8)] = hv;
        }
        // B stage: combine 4 Op quarters + normalize, swizzled ds_write
        const int hk = k0 >> 6;               // head for this k-tile (uniform)
        {
            const int row = tid >> 3, ch = tid & 7;
            const int gc = ch ^ (row & 7);
            const f16* op0 = Op + (size_t)(nBase + row) * 512 + k0 + gc * 8;
            f16x8 b0 = *(const f16x8*)(op0);
            f16x8 b1 = *(const f16x8*)(op0 + 2097152);
            f16x8 b2 = *(const f16x8*)(op0 + 4194304);
            f16x8 b3 = *(const f16x8*)(op0 + 6291456);
            const f16 iv = (f16)invL[row * 8 + hk];
            f16x8 bsum = (b0 + b1) + (b2 + b3);
            bsum = bsum * iv;
            *(f16x8*)&Bs[tid * 8] = bsum;
        }
        __syncthreads();
        for (int ks = 0; ks < 2; ks++) {
            const int chv = ((ks * 4 + g) ^ swz) * 8;
            f16x8 af[2], bf;
            for (int t = 0; t < 2; t++)
                af[t] = *(const f16x8*)&As[(wm * 32 + t * 16 + l16) * 64 + chv];
            bf = *(const f16x8*)&Bs[(wn * 16 + l16) * 64 + chv];
            for (int mt = 0; mt < 2; mt++)
                acc[mt] = MFMA32(af[mt], bf, acc[mt]);
        }
        __syncthreads();
    }

    for (int mt = 0; mt < 2; mt++)
        for (int r = 0; r < 4; r++) {
            const int o = mBase + wm * 32 + mt * 16 + g * 4 + r;
            const float bb = bias[o];
            const int p = nBase + wn * 16 + l16;
            C[(size_t)o * 4096 + p] = acc[mt][r] + bb;
        }
}

// ---------------------------------------------------------------------------
extern "C" void kernel_launch(void* const* d_in, const int* in_sizes, int n_in,
                              void* d_out, int out_size, void* d_ws, size_t ws_size,
                              hipStream_t stream) {
    const float* x    = (const float*)d_in[0];  // (1,256,64,64)
    const float* wqkv = (const float*)d_in[1];  // (1536,256)
    const float* wout = (const float*)d_in[2];  // (256,512)
    const float* bout = (const float*)d_in[3];  // (256,)
    float* out = (float*)d_out;                 // (1,256,64,64)

    char* ws = (char*)d_ws;
    // lifetime-packed workspace (30 MB):
    float* Lp = (float*)(ws);                    // [0,512K) written by attn
    f16* qb = (f16*)(ws + (2u << 20));           // [2M,6M)
    f16* kb = (f16*)(ws + (6u << 20));           // [6M,10M)
    f16* vb = (f16*)(ws + (10u << 20));          // [10M,14M) [head][d][p]
    f16* Op = (f16*)(ws + (14u << 20));          // [14M,30M) 4 split quarters

    gemm_qkv<<<dim3(64, 12), 256, 0, stream>>>(wqkv, x, qb, kb, vb);
    attn_fwd<<<dim3(512), 256, 0, stream>>>(qb, kb, vb, Op, Lp);
    gemm_out<<<dim3(128, 4), 256, 0, stream>>>(wout, Op, Lp, bout, out);
}